// Round 5
// baseline (371.750 us; speedup 1.0000x reference)
//
#include <hip/hip_runtime.h>
#include <math.h>

// Match numpy's non-FMA evaluation of the distance formula (ranking fidelity).
#pragma clang fp contract(off)

#define NPTS 4096
#define KNN  16
#define RPW  2                    // rows per wave in knn (amortize LDS Q-reads)
#define KWAVES 8                  // waves per knn block
#define KT   (KWAVES * 64)        // 512 threads
#define RPBK (KWAVES * RPW)       // 16 rows per block
#define CAP  128                  // phase-2 filtered-candidate capacity per row
#define CAP2 96                   // per-row edge bucket capacity (16 out + indeg)

// ordered-uint transform: monotone map f32 -> u32 (canonicalize -0 -> +0 first)
__device__ __forceinline__ unsigned okey(float f) {
    f = f + 0.0f;
    unsigned u = __float_as_uint(f);
    return u ^ (((unsigned)((int)u >> 31)) | 0x80000000u);
}

__device__ __forceinline__ unsigned wmin32(unsigned v) {
    for (int o = 32; o > 0; o >>= 1) { unsigned w = __shfl_xor(v, o); v = w < v ? w : v; }
    return v;
}
__device__ __forceinline__ unsigned long long wmin64(unsigned long long v) {
    for (int o = 32; o > 0; o >>= 1) { unsigned long long w = __shfl_xor(v, o); v = w < v ? w : v; }
    return v;
}

// ---------------------------------------------------------------------------
// Zero Dsum[BN] and cnt[BN] (ws is poisoned 0xAA before every call).
// ---------------------------------------------------------------------------
__global__ void zero_kernel(float* __restrict__ Dsum, int* __restrict__ cnt, int n) {
    int i = blockIdx.x * blockDim.x + threadIdx.x;
    if (i < n) { Dsum[i] = 0.0f; cnt[i] = 0; }
}

// ---------------------------------------------------------------------------
// KNN via threshold-filter + exact small select. One wave per RPW(=2) rows.
// Selection key is lexicographic (okey(d2_formula), idx) == lax.top_k order.
// Emits edges into per-row buckets (both directions) + degree halves.
// ---------------------------------------------------------------------------
__global__ __launch_bounds__(KT, 4) void knn_kernel(const float* __restrict__ xyz,
                                                    float* __restrict__ Dsum,
                                                    int* __restrict__ cnt,
                                                    int* __restrict__ cols,
                                                    float* __restrict__ vals) {
    __shared__ float4 spts[NPTS];            // 64 KB: (x,y,z,|p|^2)
    __shared__ int    lists[RPBK][CAP];      // 8 KB

    const int t    = threadIdx.x;
    const int lane = t & 63;
    const int wv   = t >> 6;
    const int row0 = blockIdx.x * RPBK + wv * RPW;        // first of this wave's rows
    const int b    = row0 >> 12;                          // block spans one batch
    const float* X = xyz + (size_t)b * 3 * NPTS;

    for (int i = t; i < NPTS; i += KT) {
        float x = X[i], y = X[NPTS + i], z = X[2 * NPTS + i];
        spts[i] = make_float4(x, y, z, (x * x + y * y) + z * z);   // numpy order
    }
    __syncthreads();

    const float4 P0 = spts[(row0 + 0) & (NPTS - 1)];
    const float4 P1 = spts[(row0 + 1) & (NPTS - 1)];

    // ---- phase 1: per-lane chunk minima; T = 16th smallest lane-min ----
    unsigned b0 = 0xFFFFFFFFu, b1 = 0xFFFFFFFFu;
    for (int i = 0; i < NPTS / 64; ++i) {
        float4 Q   = spts[i * 64 + lane];
        float dot0 = (P0.x * Q.x + P0.y * Q.y) + P0.z * Q.z;       // einsum order
        float dot1 = (P1.x * Q.x + P1.y * Q.y) + P1.z * Q.z;
        unsigned k0 = okey((P0.w + Q.w) - 2.0f * dot0);            // (sq+sq)-2dot
        unsigned k1 = okey((P1.w + Q.w) - 2.0f * dot1);
        b0 = k0 < b0 ? k0 : b0;
        b1 = k1 < b1 ? k1 : b1;
    }
    unsigned T0 = 0, T1 = 0;
    {
        unsigned cur = b0;
        for (int r = 0; r < KNN; ++r) { unsigned mn = wmin32(cur); T0 = mn; if (cur == mn) cur = 0xFFFFFFFFu; }
        cur = b1;
        for (int r = 0; r < KNN; ++r) { unsigned mn = wmin32(cur); T1 = mn; if (cur == mn) cur = 0xFFFFFFFFu; }
    }

    // ---- phase 2: filter candidates with key <= T into LDS lists ----
    int cnt0 = 0, cnt1 = 0;
    for (int i = 0; i < NPTS / 64; ++i) {
        int m = i * 64 + lane;
        float4 Q   = spts[m];
        float dot0 = (P0.x * Q.x + P0.y * Q.y) + P0.z * Q.z;
        float dot1 = (P1.x * Q.x + P1.y * Q.y) + P1.z * Q.z;
        bool p0 = okey((P0.w + Q.w) - 2.0f * dot0) <= T0;
        bool p1 = okey((P1.w + Q.w) - 2.0f * dot1) <= T1;
        unsigned long long bal0 = __ballot(p0);
        unsigned long long bal1 = __ballot(p1);
        if (p0) {
            int pos = cnt0 + __popcll(bal0 & ((1ull << lane) - 1ull));
            if (pos < CAP) lists[wv * RPW + 0][pos] = m;
        }
        if (p1) {
            int pos = cnt1 + __popcll(bal1 & ((1ull << lane) - 1ull));
            if (pos < CAP) lists[wv * RPW + 1][pos] = m;
        }
        cnt0 += (int)__popcll(bal0);
        cnt1 += (int)__popcll(bal1);
    }

    // ---- phase 3 + edge emission, per row ----
    for (int r = 0; r < RPW; ++r) {
        const int rowg = row0 + r;
        const int nloc = rowg & (NPTS - 1);
        const float4 P = r == 0 ? P0 : P1;
        const int cn   = r == 0 ? cnt0 : cnt1;
        const int lr   = wv * RPW + r;

        unsigned long long sel = ~0ull;
        if (cn <= CAP) {
            unsigned long long e0 = ~0ull, e1 = ~0ull;
            if (lane < cn) {
                int m = lists[lr][lane]; float4 Q = spts[m];
                float dot = (P.x * Q.x + P.y * Q.y) + P.z * Q.z;
                float d2  = (P.w + Q.w) - 2.0f * dot;
                e0 = ((unsigned long long)okey(d2) << 32) | (unsigned)m;
            }
            if (lane + 64 < cn) {
                int m = lists[lr][lane + 64]; float4 Q = spts[m];
                float dot = (P.x * Q.x + P.y * Q.y) + P.z * Q.z;
                float d2  = (P.w + Q.w) - 2.0f * dot;
                e1 = ((unsigned long long)okey(d2) << 32) | (unsigned)m;
            }
            unsigned long long c = e0 < e1 ? e0 : e1;
            for (int k = 0; k < KNN; ++k) {
                unsigned long long mn = wmin64(c);
                if (c == mn) {                      // keys unique -> one lane
                    if (e0 == mn) e0 = ~0ull; else e1 = ~0ull;
                    c = e0 < e1 ? e0 : e1;
                }
                if (lane == k) sel = mn;
            }
        } else {
            // overflow fallback (astronomically rare): exact 16 rounds of
            // strictly-increasing wave-min over the full candidate set
            unsigned long long last = 0;
            for (int k = 0; k < KNN; ++k) {
                unsigned long long bestp = ~0ull;
                for (int i = 0; i < NPTS / 64; ++i) {
                    int m = i * 64 + lane;
                    float4 Q  = spts[m];
                    float dot = (P.x * Q.x + P.y * Q.y) + P.z * Q.z;
                    float d2  = (P.w + Q.w) - 2.0f * dot;
                    unsigned long long key = ((unsigned long long)okey(d2) << 32) | (unsigned)m;
                    if (key > last && key < bestp) bestp = key;
                }
                unsigned long long mn = wmin64(bestp);
                if (lane == k) sel = mn;
                last = mn;
            }
        }

        // winners on lanes 0..15: exact-diff weight, degree halves, edge pushes
        float wgt = 0.0f;
        if (lane < KNN) {
            int j = (int)(unsigned)(sel & 0xFFFFFFFFull);
            float4 Q = spts[j];
            float dx = P.x - Q.x, dy = P.y - Q.y, dz = P.z - Q.z;
            float dist2 = (dx * dx + dy * dy) + dz * dz;            // numpy order
            wgt = expf(-(dist2 * 0.5f));
            float hw = 0.5f * wgt;
            int jg = (b << 12) + j;
            atomicAdd(&Dsum[jg], hw);                               // transpose half
            // push half-edges to both row buckets
            int p0 = atomicAdd(&cnt[rowg], 1);
            if (p0 < CAP2) { cols[(size_t)rowg * CAP2 + p0] = j;    vals[(size_t)rowg * CAP2 + p0] = hw; }
            int p1 = atomicAdd(&cnt[jg], 1);
            if (p1 < CAP2) { cols[(size_t)jg * CAP2 + p1] = nloc;   vals[(size_t)jg * CAP2 + p1] = hw; }
        }
        float rs = wgt;
        for (int o = 32; o > 0; o >>= 1) rs += __shfl_xor(rs, o);
        if (lane == 0) atomicAdd(&Dsum[rowg], 0.5f * rs);           // outgoing half
    }
}

// ---------------------------------------------------------------------------
// Row-owner writer: one block per row. Accumulate scaled sparse entries in a
// 16 KB LDS row (LDS atomics, handles duplicate cols), then stream
// L[r,c] = delta(r,c) - acc[c] to HBM with float4 stores. No global atomics;
// the 256 MB output is written exactly once.
// ---------------------------------------------------------------------------
__global__ __launch_bounds__(256) void rowwrite_kernel(const int* __restrict__ cnt,
                                                       const int* __restrict__ cols,
                                                       const float* __restrict__ vals,
                                                       const float* __restrict__ Dsum,
                                                       float* __restrict__ L) {
    __shared__ float acc[NPTS];              // 16 KB
    const int t  = threadIdx.x;
    const int r  = blockIdx.x;               // global row 0..BN-1
    const int b  = r >> 12;
    const int rl = r & (NPTS - 1);

    for (int i = t; i < NPTS; i += 256) acc[i] = 0.0f;
    __syncthreads();

    int c_ = cnt[r]; if (c_ > CAP2) c_ = CAP2;
    float sn = 1.0f / sqrtf(fmaxf(Dsum[r], 1e-6f));
    for (int e = t; e < c_; e += 256) {
        int   c = cols[(size_t)r * CAP2 + e];
        float v = vals[(size_t)r * CAP2 + e];
        float sc = 1.0f / sqrtf(fmaxf(Dsum[(b << 12) + c], 1e-6f));
        atomicAdd(&acc[c], v * sn * sc);
    }
    __syncthreads();

    float4* out4 = (float4*)(L + (size_t)b * NPTS * NPTS + (size_t)rl * NPTS);
    const float4* a4 = (const float4*)acc;
    for (int i4 = t; i4 < NPTS / 4; i4 += 256) {
        float4 a = a4[i4];
        int c0 = i4 << 2;
        float4 v;
        v.x = ((c0 + 0) == rl ? 1.0f : 0.0f) - a.x;
        v.y = ((c0 + 1) == rl ? 1.0f : 0.0f) - a.y;
        v.z = ((c0 + 2) == rl ? 1.0f : 0.0f) - a.z;
        v.w = ((c0 + 3) == rl ? 1.0f : 0.0f) - a.w;
        out4[i4] = v;
    }
}

// ---------------------------------------------------------------------------
extern "C" void kernel_launch(void* const* d_in, const int* in_sizes, int n_in,
                              void* d_out, int out_size, void* d_ws, size_t ws_size,
                              hipStream_t stream) {
    const float* xyz = (const float*)d_in[0];
    const int B  = in_sizes[0] / (3 * NPTS);            // 4
    const int BN = B * NPTS;                            // 16384

    // workspace: Dsum[BN] f32 | cnt[BN] i32 | cols[BN*CAP2] i32 | vals[BN*CAP2] f32
    float* Dsum = (float*)d_ws;
    int*   cnt  = (int*)(Dsum + BN);
    int*   cols = cnt + BN;
    float* vals = (float*)(cols + (size_t)BN * CAP2);
    float* L    = (float*)d_out;

    zero_kernel<<<BN / 256, 256, 0, stream>>>(Dsum, cnt, BN);
    knn_kernel<<<BN / RPBK, KT, 0, stream>>>(xyz, Dsum, cnt, cols, vals);
    rowwrite_kernel<<<BN, 256, 0, stream>>>(cnt, cols, vals, Dsum, L);
}